// Round 1
// baseline (188.331 us; speedup 1.0000x reference)
//
#include <hip/hip_runtime.h>
#include <math.h>

#define BB 2
#define LL 5
#define NN 10
#define CC 64
#define HH 128
#define WW 256
#define PP (HH*WW)          // 32768 pixels
#define NP (NN*PP)          // 327680

// ---------------- ws float layout ----------------
// [0..15]    enw
// [16..31]   enc
// [32]       cnt (mask count)
// [64..191]  avg_sum (B*C)
// [192..319] mx      (B*C)
// [320..447] gate    (B*C)
// [1024 .. 1024+NP)        mask
// [1024+NP .. 1024+2*NP)   conf

__global__ void k_init(const float* __restrict__ inv_delay,
                       const float* __restrict__ ew_w, const float* __restrict__ ew_b,
                       const float* __restrict__ ewc_w, const float* __restrict__ ewc_b,
                       float* __restrict__ wsf) {
    int t = threadIdx.x;
    if (t < NN) {
        float d = inv_delay[t];
        wsf[t]      = tanhf(d * ew_w[0]  + ew_b[0])  + 1.0f;  // enw
        wsf[16 + t] = tanhf(d * ewc_w[0] + ewc_b[0]) + 1.0f;  // enc
    }
    if (t == 0) wsf[32] = 0.0f;
}

__global__ void k_conf(const float* __restrict__ psm,
                       const float* __restrict__ enc,
                       float* __restrict__ conf) {
    int i = blockIdx.x * 256 + threadIdx.x;   // < NP
    int n = i >> 15;                          // / PP
    int p = i & (PP - 1);
    float a0 = psm[(n * 2 + 0) * PP + p];
    float a1 = psm[(n * 2 + 1) * PP + p];
    float s0 = 1.0f / (1.0f + expf(-a0));
    float s1 = 1.0f / (1.0f + expf(-a1));
    conf[i] = fmaxf(s0, s1) * enc[n];
}

__global__ void k_mask(const float* __restrict__ conf,
                       float* __restrict__ mask,
                       float* __restrict__ cnt) {
    // gaussian taps: 1/(2*pi*sigma) * exp(-d2/2), sigma=1 (f64-derived, rounded to f32)
    const float g0 = 0.15915494309189535f;   // d2=0
    const float g1 = 0.09653235263005391f;   // d2=1
    const float g2 = 0.05854983152431917f;   // d2=2
    const float g4 = 0.02153927930184936f;   // d2=4
    const float g5 = 0.01306423328468446f;   // d2=5
    const float g8 = 0.00291502449738744f;   // d2=8
    const float G[25] = { g8,g5,g4,g5,g8,
                          g5,g2,g1,g2,g5,
                          g4,g1,g0,g1,g4,
                          g5,g2,g1,g2,g5,
                          g8,g5,g4,g5,g8 };
    int i = blockIdx.x * 256 + threadIdx.x;   // < NP
    int n  = i >> 15;
    int hw = i & (PP - 1);
    int h = hw >> 8;          // W=256
    int w = hw & 255;
    const float* cn = conf + n * PP;
    float acc = 0.0f;
#pragma unroll
    for (int dy = -2; dy <= 2; ++dy) {
        int hh = h + dy;
        if ((unsigned)hh < (unsigned)HH) {
#pragma unroll
            for (int dx = -2; dx <= 2; ++dx) {
                int ww = w + dx;
                if ((unsigned)ww < (unsigned)WW)
                    acc += cn[hh * WW + ww] * G[(dy + 2) * 5 + (dx + 2)];
            }
        }
    }
    float mv = (acc > 0.01f) ? 1.0f : 0.0f;
    if ((n % LL) == 0) mv = 1.0f;             // ego always communicates
    mask[i] = mv;

    // block-reduce count, one atomic per block
    float v = mv;
#pragma unroll
    for (int o = 32; o > 0; o >>= 1) v += __shfl_down(v, o, 64);
    __shared__ float sred[4];
    int lane = threadIdx.x & 63, wid = threadIdx.x >> 6;
    if (lane == 0) sred[wid] = v;
    __syncthreads();
    if (threadIdx.x == 0) {
        float s = sred[0] + sred[1] + sred[2] + sred[3];
        atomicAdd(cnt, s);
    }
}

__global__ __launch_bounds__(256) void k_attn(const float* __restrict__ x,
                                              const float* __restrict__ mask,
                                              const float* __restrict__ enw,
                                              float* __restrict__ xfuse) {
    int idx = blockIdx.x * 256 + threadIdx.x; // < B*PP
    int b = idx >> 15;
    int p = idx & (PP - 1);
    const float* xb = x + b * (LL * CC * PP);
    const float* mb = mask + b * (LL * PP);

    float m0 = enw[b * LL + 0] * mb[0 * PP + p];
    float m1 = enw[b * LL + 1] * mb[1 * PP + p];
    float m2 = enw[b * LL + 2] * mb[2 * PP + p];
    float m3 = enw[b * LL + 3] * mb[3 * PP + p];
    float m4 = enw[b * LL + 4] * mb[4 * PP + p];

    float q[CC];
    float s0 = 0.f, s1 = 0.f, s2 = 0.f, s3 = 0.f, s4 = 0.f;
#pragma unroll
    for (int c = 0; c < CC; ++c) {
        const float* xc = xb + c * PP + p;
        float v0 = xc[0];
        q[c] = v0;
        s0 += v0 * v0;
        s1 += v0 * xc[1 * CC * PP];
        s2 += v0 * xc[2 * CC * PP];
        s3 += v0 * xc[3 * CC * PP];
        s4 += v0 * xc[4 * CC * PP];
    }
    const float scale = 0.125f;               // 1/sqrt(64)
    float sc0 = s0 * m0 * m0 * scale;
    float sc1 = s1 * m0 * m1 * scale;
    float sc2 = s2 * m0 * m2 * scale;
    float sc3 = s3 * m0 * m3 * scale;
    float sc4 = s4 * m0 * m4 * scale;
    float mxv = fmaxf(fmaxf(fmaxf(sc0, sc1), fmaxf(sc2, sc3)), sc4);
    float e0 = expf(sc0 - mxv);
    float e1 = expf(sc1 - mxv);
    float e2 = expf(sc2 - mxv);
    float e3 = expf(sc3 - mxv);
    float e4 = expf(sc4 - mxv);
    float inv = 1.0f / (e0 + e1 + e2 + e3 + e4);
    float a0 = e0 * inv * m0;
    float a1 = e1 * inv * m1;
    float a2 = e2 * inv * m2;
    float a3 = e3 * inv * m3;
    float a4 = e4 * inv * m4;

    float* ob = xfuse + b * (CC * PP) + p;
#pragma unroll
    for (int c = 0; c < CC; ++c) {
        const float* xc = xb + c * PP + p;
        float f = a0 * q[c]
                + a1 * xc[1 * CC * PP]
                + a2 * xc[2 * CC * PP]
                + a3 * xc[3 * CC * PP]
                + a4 * xc[4 * CC * PP];
        ob[c * PP] = f;
    }
}

__global__ void k_reduce(const float* __restrict__ xfuse,
                         float* __restrict__ avg_sum,
                         float* __restrict__ mxv) {
    int bc = blockIdx.x;                      // 0..B*C-1
    const float4* row = (const float4*)(xfuse + bc * PP);
    float s = 0.0f, m = -INFINITY;
    for (int i = threadIdx.x; i < PP / 4; i += 256) {
        float4 v = row[i];
        s += v.x + v.y + v.z + v.w;
        m = fmaxf(m, fmaxf(fmaxf(v.x, v.y), fmaxf(v.z, v.w)));
    }
#pragma unroll
    for (int o = 32; o > 0; o >>= 1) {
        s += __shfl_down(s, o, 64);
        m = fmaxf(m, __shfl_down(m, o, 64));
    }
    __shared__ float ss[4], sm[4];
    int lane = threadIdx.x & 63, wid = threadIdx.x >> 6;
    if (lane == 0) { ss[wid] = s; sm[wid] = m; }
    __syncthreads();
    if (threadIdx.x == 0) {
        avg_sum[bc] = ss[0] + ss[1] + ss[2] + ss[3];
        mxv[bc]     = fmaxf(fmaxf(sm[0], sm[1]), fmaxf(sm[2], sm[3]));
    }
}

__global__ void k_gate(const float* __restrict__ avg_sum,
                       const float* __restrict__ mxv,
                       const float* __restrict__ w1,   // (4,64)
                       const float* __restrict__ w2,   // (64,4)
                       float* __restrict__ gate,
                       const float* __restrict__ cnt,
                       float* __restrict__ comm_out) {
    __shared__ float hsum[BB][4];
    int t = threadIdx.x;
    if (t < BB * 4) {
        int b = t >> 2, j = t & 3;
        float ha = 0.f, hm = 0.f;
        for (int c = 0; c < CC; ++c) {
            float wv = w1[j * CC + c];
            ha += (avg_sum[b * CC + c] * (1.0f / (float)PP)) * wv;
            hm += mxv[b * CC + c] * wv;
        }
        hsum[b][j] = fmaxf(ha, 0.0f) + fmaxf(hm, 0.0f);
    }
    __syncthreads();
    if (t < BB * CC) {
        int b = t >> 6, c = t & 63;
        float g = 0.f;
#pragma unroll
        for (int j = 0; j < 4; ++j) g += hsum[b][j] * w2[c * 4 + j];
        gate[t] = 1.0f / (1.0f + expf(-g));
    }
    if (t == 0) comm_out[0] = cnt[0] * (1.0f / (float)NP);
}

__global__ void k_scale(float* __restrict__ out, const float* __restrict__ gate) {
    int i = blockIdx.x * 256 + threadIdx.x;   // over B*C*P/4
    int bc = i >> 13;                         // (i*4)/PP
    float g = gate[bc];
    float4* o = (float4*)out;
    float4 v = o[i];
    v.x *= g; v.y *= g; v.z *= g; v.w *= g;
    o[i] = v;
}

extern "C" void kernel_launch(void* const* d_in, const int* in_sizes, int n_in,
                              void* d_out, int out_size, void* d_ws, size_t ws_size,
                              hipStream_t stream) {
    const float* x         = (const float*)d_in[0];
    const float* psm       = (const float*)d_in[1];
    const float* inv_delay = (const float*)d_in[2];
    const float* ew_w      = (const float*)d_in[3];
    const float* ew_b      = (const float*)d_in[4];
    const float* ewc_w     = (const float*)d_in[5];
    const float* ewc_b     = (const float*)d_in[6];
    const float* w1        = (const float*)d_in[7];
    const float* w2        = (const float*)d_in[8];
    float* out = (float*)d_out;
    float* wsf = (float*)d_ws;

    float* enw  = wsf;
    float* enc  = wsf + 16;
    float* cnt  = wsf + 32;
    float* avg  = wsf + 64;
    float* mxv  = wsf + 192;
    float* gate = wsf + 320;
    float* mask = wsf + 1024;
    float* conf = wsf + 1024 + NP;

    k_init<<<1, 64, 0, stream>>>(inv_delay, ew_w, ew_b, ewc_w, ewc_b, wsf);
    k_conf<<<NP / 256, 256, 0, stream>>>(psm, enc, conf);
    k_mask<<<NP / 256, 256, 0, stream>>>(conf, mask, cnt);
    k_attn<<<BB * PP / 256, 256, 0, stream>>>(x, mask, enw, out);
    k_reduce<<<BB * CC, 256, 0, stream>>>(out, avg, mxv);
    k_gate<<<1, 128, 0, stream>>>(avg, mxv, w1, w2, gate, cnt, out + BB * CC * PP);
    k_scale<<<BB * CC * PP / 4 / 256, 256, 0, stream>>>(out, gate);
}

// Round 2
// 89.227 us; speedup vs baseline: 2.1107x; 2.1107x over previous
//
#include <hip/hip_runtime.h>
#include <math.h>

#define BB 2
#define LL 5
#define NN 10
#define CC 64
#define HH 128
#define WW 256
#define PP (HH*WW)          // 32768 pixels
#define NP (NN*PP)          // 327680

// ---------------- ws float layout ----------------
// [0..15]    enw
// [16..31]   enc
// [32]       cnt (mask count)
// [64..319]  avg_part (256)
// [320..575] mx_part  (256)
// [576..703] gate     (B*C)
// [1024 .. 1024+NP)        mask
// [1024+NP .. 1024+2*NP)   conf, reused as attn after k_mask

__global__ void k_init(const float* __restrict__ inv_delay,
                       const float* __restrict__ ew_w, const float* __restrict__ ew_b,
                       const float* __restrict__ ewc_w, const float* __restrict__ ewc_b,
                       float* __restrict__ wsf) {
    int t = threadIdx.x;
    if (t < NN) {
        float d = inv_delay[t];
        wsf[t]      = tanhf(d * ew_w[0]  + ew_b[0])  + 1.0f;  // enw
        wsf[16 + t] = tanhf(d * ewc_w[0] + ewc_b[0]) + 1.0f;  // enc
    }
    if (t == 0) wsf[32] = 0.0f;
}

__global__ void k_conf(const float* __restrict__ psm,
                       const float* __restrict__ enc,
                       float* __restrict__ conf) {
    int i = blockIdx.x * 256 + threadIdx.x;   // < NP
    int n = i >> 15;                          // / PP
    int p = i & (PP - 1);
    float a0 = psm[(n * 2 + 0) * PP + p];
    float a1 = psm[(n * 2 + 1) * PP + p];
    float s0 = 1.0f / (1.0f + expf(-a0));
    float s1 = 1.0f / (1.0f + expf(-a1));
    conf[i] = fmaxf(s0, s1) * enc[n];
}

__global__ void k_mask(const float* __restrict__ conf,
                       float* __restrict__ mask,
                       float* __restrict__ cnt) {
    const float g0 = 0.15915494309189535f;   // d2=0
    const float g1 = 0.09653235263005391f;   // d2=1
    const float g2 = 0.05854983152431917f;   // d2=2
    const float g4 = 0.02153927930184936f;   // d2=4
    const float g5 = 0.01306423328468446f;   // d2=5
    const float g8 = 0.00291502449738744f;   // d2=8
    const float G[25] = { g8,g5,g4,g5,g8,
                          g5,g2,g1,g2,g5,
                          g4,g1,g0,g1,g4,
                          g5,g2,g1,g2,g5,
                          g8,g5,g4,g5,g8 };
    int i = blockIdx.x * 256 + threadIdx.x;   // < NP
    int n  = i >> 15;
    int hw = i & (PP - 1);
    int h = hw >> 8;
    int w = hw & 255;
    const float* cn = conf + n * PP;
    float acc = 0.0f;
#pragma unroll
    for (int dy = -2; dy <= 2; ++dy) {
        int hh = h + dy;
        if ((unsigned)hh < (unsigned)HH) {
#pragma unroll
            for (int dx = -2; dx <= 2; ++dx) {
                int ww = w + dx;
                if ((unsigned)ww < (unsigned)WW)
                    acc += cn[hh * WW + ww] * G[(dy + 2) * 5 + (dx + 2)];
            }
        }
    }
    float mv = (acc > 0.01f) ? 1.0f : 0.0f;
    if ((n % LL) == 0) mv = 1.0f;
    mask[i] = mv;

    float v = mv;
#pragma unroll
    for (int o = 32; o > 0; o >>= 1) v += __shfl_down(v, o, 64);
    __shared__ float sred[4];
    int lane = threadIdx.x & 63, wid = threadIdx.x >> 6;
    if (lane == 0) sred[wid] = v;
    __syncthreads();
    if (threadIdx.x == 0) {
        float s = sred[0] + sred[1] + sred[2] + sred[3];
        atomicAdd(cnt, s);
    }
}

// scores + masked softmax -> attn[b][l][p]
// 1024 blocks x 256 threads; block = 64 pixels; wave wv owns channels [16*wv, 16*wv+16)
__global__ __launch_bounds__(256) void k_scores(const float* __restrict__ x,
                                                const float* __restrict__ mask,
                                                const float* __restrict__ enw,
                                                float* __restrict__ attn) {
    int blk = blockIdx.x;
    int b   = blk >> 9;                 // 512 blocks per batch
    int p   = ((blk & 511) << 6) + (threadIdx.x & 63);
    int wv  = threadIdx.x >> 6;
    const float* xb = x + b * (LL * CC * PP) + p;

    float s0 = 0.f, s1 = 0.f, s2 = 0.f, s3 = 0.f, s4 = 0.f;
    int cbase = wv << 4;
#pragma unroll
    for (int cc = 0; cc < 16; ++cc) {
        const float* xc = xb + (cbase + cc) * PP;
        float q = xc[0];
        s0 += q * q;
        s1 += q * xc[1 * CC * PP];
        s2 += q * xc[2 * CC * PP];
        s3 += q * xc[3 * CC * PP];
        s4 += q * xc[4 * CC * PP];
    }
    __shared__ float sred[4][5][64];
    int lane = threadIdx.x & 63;
    sred[wv][0][lane] = s0;
    sred[wv][1][lane] = s1;
    sred[wv][2][lane] = s2;
    sred[wv][3][lane] = s3;
    sred[wv][4][lane] = s4;
    __syncthreads();
    if (wv == 0) {
        float t0 = sred[0][0][lane] + sred[1][0][lane] + sred[2][0][lane] + sred[3][0][lane];
        float t1 = sred[0][1][lane] + sred[1][1][lane] + sred[2][1][lane] + sred[3][1][lane];
        float t2 = sred[0][2][lane] + sred[1][2][lane] + sred[2][2][lane] + sred[3][2][lane];
        float t3 = sred[0][3][lane] + sred[1][3][lane] + sred[2][3][lane] + sred[3][3][lane];
        float t4 = sred[0][4][lane] + sred[1][4][lane] + sred[2][4][lane] + sred[3][4][lane];
        const float* mb = mask + b * (LL * PP) + p;
        float m0 = enw[b * LL + 0] * mb[0];
        float m1 = enw[b * LL + 1] * mb[1 * PP];
        float m2 = enw[b * LL + 2] * mb[2 * PP];
        float m3 = enw[b * LL + 3] * mb[3 * PP];
        float m4 = enw[b * LL + 4] * mb[4 * PP];
        const float scale = 0.125f;
        float sc0 = t0 * m0 * m0 * scale;
        float sc1 = t1 * m0 * m1 * scale;
        float sc2 = t2 * m0 * m2 * scale;
        float sc3 = t3 * m0 * m3 * scale;
        float sc4 = t4 * m0 * m4 * scale;
        float mxv = fmaxf(fmaxf(fmaxf(sc0, sc1), fmaxf(sc2, sc3)), sc4);
        float e0 = expf(sc0 - mxv);
        float e1 = expf(sc1 - mxv);
        float e2 = expf(sc2 - mxv);
        float e3 = expf(sc3 - mxv);
        float e4 = expf(sc4 - mxv);
        float inv = 1.0f / (e0 + e1 + e2 + e3 + e4);
        float* ab = attn + b * (LL * PP) + p;
        ab[0 * PP] = e0 * inv * m0;
        ab[1 * PP] = e1 * inv * m1;
        ab[2 * PP] = e2 * inv * m2;
        ab[3 * PP] = e3 * inv * m3;
        ab[4 * PP] = e4 * inv * m4;
    }
}

// fused output: one float4 per thread over (b,c,p)
__global__ __launch_bounds__(256) void k_fuse(const float* __restrict__ x,
                                              const float* __restrict__ attn,
                                              float* __restrict__ out) {
    int idx = blockIdx.x * 256 + threadIdx.x;   // < B*C*PP/4 = 1048576
    int bc = idx >> 13;                         // PP/4 = 8192
    int b  = bc >> 6;
    int c  = bc & 63;
    int p4 = idx & 8191;
    const float4* xb = (const float4*)(x + (b * LL * CC + c) * PP) + p4;
    const float4* ab = (const float4*)(attn + b * LL * PP) + p4;
    float4 acc = {0.f, 0.f, 0.f, 0.f};
#pragma unroll
    for (int l = 0; l < LL; ++l) {
        float4 xv = xb[l * CC * PP / 4];
        float4 av = ab[l * PP / 4];
        acc.x += av.x * xv.x;
        acc.y += av.y * xv.y;
        acc.z += av.z * xv.z;
        acc.w += av.w * xv.w;
    }
    ((float4*)out)[idx] = acc;
}

// 256 blocks: block = half of one (b,c) row -> partials
__global__ void k_reduce(const float* __restrict__ xfuse,
                         float* __restrict__ avg_part,
                         float* __restrict__ mx_part) {
    int blk = blockIdx.x;               // 256
    int bc = blk >> 1;
    int half = blk & 1;
    const float4* row = (const float4*)(xfuse + bc * PP) + half * 4096;
    float s = 0.0f, m = -INFINITY;
    for (int i = threadIdx.x; i < 4096; i += 256) {
        float4 v = row[i];
        s += v.x + v.y + v.z + v.w;
        m = fmaxf(m, fmaxf(fmaxf(v.x, v.y), fmaxf(v.z, v.w)));
    }
#pragma unroll
    for (int o = 32; o > 0; o >>= 1) {
        s += __shfl_down(s, o, 64);
        m = fmaxf(m, __shfl_down(m, o, 64));
    }
    __shared__ float ss[4], sm[4];
    int lane = threadIdx.x & 63, wid = threadIdx.x >> 6;
    if (lane == 0) { ss[wid] = s; sm[wid] = m; }
    __syncthreads();
    if (threadIdx.x == 0) {
        avg_part[blk] = ss[0] + ss[1] + ss[2] + ss[3];
        mx_part[blk]  = fmaxf(fmaxf(sm[0], sm[1]), fmaxf(sm[2], sm[3]));
    }
}

__global__ void k_gate(const float* __restrict__ avg_part,
                       const float* __restrict__ mx_part,
                       const float* __restrict__ w1,   // (4,64)
                       const float* __restrict__ w2,   // (64,4)
                       float* __restrict__ gate,
                       const float* __restrict__ cnt,
                       float* __restrict__ comm_out) {
    __shared__ float hsum[BB][4];
    int t = threadIdx.x;
    if (t < BB * 4) {
        int b = t >> 2, j = t & 3;
        float ha = 0.f, hm = 0.f;
        for (int c = 0; c < CC; ++c) {
            int i = (b * CC + c) * 2;
            float av = (avg_part[i] + avg_part[i + 1]) * (1.0f / (float)PP);
            float mv = fmaxf(mx_part[i], mx_part[i + 1]);
            float wv = w1[j * CC + c];
            ha += av * wv;
            hm += mv * wv;
        }
        hsum[b][j] = fmaxf(ha, 0.0f) + fmaxf(hm, 0.0f);
    }
    __syncthreads();
    if (t < BB * CC) {
        int b = t >> 6, c = t & 63;
        float g = 0.f;
#pragma unroll
        for (int j = 0; j < 4; ++j) g += hsum[b][j] * w2[c * 4 + j];
        gate[t] = 1.0f / (1.0f + expf(-g));
    }
    if (t == 0) comm_out[0] = cnt[0] * (1.0f / (float)NP);
}

__global__ void k_scale(float* __restrict__ out, const float* __restrict__ gate) {
    int i = blockIdx.x * 256 + threadIdx.x;   // over B*C*P/4
    int bc = i >> 13;
    float g = gate[bc];
    float4* o = (float4*)out;
    float4 v = o[i];
    v.x *= g; v.y *= g; v.z *= g; v.w *= g;
    o[i] = v;
}

extern "C" void kernel_launch(void* const* d_in, const int* in_sizes, int n_in,
                              void* d_out, int out_size, void* d_ws, size_t ws_size,
                              hipStream_t stream) {
    const float* x         = (const float*)d_in[0];
    const float* psm       = (const float*)d_in[1];
    const float* inv_delay = (const float*)d_in[2];
    const float* ew_w      = (const float*)d_in[3];
    const float* ew_b      = (const float*)d_in[4];
    const float* ewc_w     = (const float*)d_in[5];
    const float* ewc_b     = (const float*)d_in[6];
    const float* w1        = (const float*)d_in[7];
    const float* w2        = (const float*)d_in[8];
    float* out = (float*)d_out;
    float* wsf = (float*)d_ws;

    float* enw  = wsf;
    float* enc  = wsf + 16;
    float* cnt  = wsf + 32;
    float* avgp = wsf + 64;
    float* mxp  = wsf + 320;
    float* gate = wsf + 576;
    float* mask = wsf + 1024;
    float* conf = wsf + 1024 + NP;   // reused as attn after k_mask
    float* attn = conf;

    k_init<<<1, 64, 0, stream>>>(inv_delay, ew_w, ew_b, ewc_w, ewc_b, wsf);
    k_conf<<<NP / 256, 256, 0, stream>>>(psm, enc, conf);
    k_mask<<<NP / 256, 256, 0, stream>>>(conf, mask, cnt);
    k_scores<<<1024, 256, 0, stream>>>(x, mask, enw, attn);
    k_fuse<<<BB * CC * PP / 4 / 256, 256, 0, stream>>>(x, attn, out);
    k_reduce<<<256, 256, 0, stream>>>(out, avgp, mxp);
    k_gate<<<1, 128, 0, stream>>>(avgp, mxp, w1, w2, gate, cnt, out + BB * CC * PP);
    k_scale<<<BB * CC * PP / 4 / 256, 256, 0, stream>>>(out, gate);
}

// Round 3
// 66.365 us; speedup vs baseline: 2.8378x; 1.3445x over previous
//
#include <hip/hip_runtime.h>
#include <math.h>

#define BB 2
#define LL 5
#define NN 10
#define CC 64
#define HH 128
#define WW 256
#define PP (HH*WW)          // 32768 pixels
#define NP (NN*PP)          // 327680

// ---------------- ws float layout ----------------
// [32]       cnt (mask count)
// [64..319]  avg_part (256)
// [320..575] mx_part  (256)
// [576..703] gate     (B*C)
// [1024 .. 1024+NP)        mask
// [1024+NP .. 1024+2*NP)   conf

// conf = max(sigmoid(psm anchors)) * enc ; also zeroes cnt
__global__ __launch_bounds__(256) void k_conf(const float* __restrict__ psm,
                                              const float* __restrict__ inv_delay,
                                              const float* __restrict__ ewc_w,
                                              const float* __restrict__ ewc_b,
                                              float* __restrict__ conf,
                                              float* __restrict__ cnt) {
    int idx = blockIdx.x * 256 + threadIdx.x;   // < NP/4
    if (idx == 0) cnt[0] = 0.0f;
    int n  = idx >> 13;                         // PP/4 = 8192
    int p4 = idx & 8191;
    const float4* psm4 = (const float4*)psm;
    float4 a0 = psm4[(n * 2 + 0) * 8192 + p4];
    float4 a1 = psm4[(n * 2 + 1) * 8192 + p4];
    float enc = tanhf(inv_delay[n] * ewc_w[0] + ewc_b[0]) + 1.0f;
    float4 r;
    r.x = fmaxf(1.0f / (1.0f + expf(-a0.x)), 1.0f / (1.0f + expf(-a1.x))) * enc;
    r.y = fmaxf(1.0f / (1.0f + expf(-a0.y)), 1.0f / (1.0f + expf(-a1.y))) * enc;
    r.z = fmaxf(1.0f / (1.0f + expf(-a0.z)), 1.0f / (1.0f + expf(-a1.z))) * enc;
    r.w = fmaxf(1.0f / (1.0f + expf(-a0.w)), 1.0f / (1.0f + expf(-a1.w))) * enc;
    ((float4*)conf)[idx] = r;
}

__global__ __launch_bounds__(256) void k_mask(const float* __restrict__ conf,
                                              float* __restrict__ mask,
                                              float* __restrict__ cnt) {
    const float g0 = 0.15915494309189535f;   // d2=0
    const float g1 = 0.09653235263005391f;   // d2=1
    const float g2 = 0.05854983152431917f;   // d2=2
    const float g4 = 0.02153927930184936f;   // d2=4
    const float g5 = 0.01306423328468446f;   // d2=5
    const float g8 = 0.00291502449738744f;   // d2=8
    const float G[25] = { g8,g5,g4,g5,g8,
                          g5,g2,g1,g2,g5,
                          g4,g1,g0,g1,g4,
                          g5,g2,g1,g2,g5,
                          g8,g5,g4,g5,g8 };
    int i = blockIdx.x * 256 + threadIdx.x;   // < NP
    int n  = i >> 15;
    int hw = i & (PP - 1);
    int h = hw >> 8;
    int w = hw & 255;
    const float* cn = conf + n * PP;
    float acc = 0.0f;
#pragma unroll
    for (int dy = -2; dy <= 2; ++dy) {
        int hh = h + dy;
        if ((unsigned)hh < (unsigned)HH) {
#pragma unroll
            for (int dx = -2; dx <= 2; ++dx) {
                int ww = w + dx;
                if ((unsigned)ww < (unsigned)WW)
                    acc += cn[hh * WW + ww] * G[(dy + 2) * 5 + (dx + 2)];
            }
        }
    }
    float mv = (acc > 0.01f) ? 1.0f : 0.0f;
    if ((n % LL) == 0) mv = 1.0f;
    mask[i] = mv;

    float v = mv;
#pragma unroll
    for (int o = 32; o > 0; o >>= 1) v += __shfl_down(v, o, 64);
    __shared__ float sred[4];
    int lane = threadIdx.x & 63, wid = threadIdx.x >> 6;
    if (lane == 0) sred[wid] = v;
    __syncthreads();
    if (threadIdx.x == 0) {
        float s = sred[0] + sred[1] + sred[2] + sred[3];
        atomicAdd(cnt, s);
    }
}

// scores + softmax + fuse, x read exactly once (kept in registers).
// 1024 blocks x 256 thr; block = 64 pixels; wave wv owns channels [16wv,16wv+16)
__global__ __launch_bounds__(256) void k_attnfuse(const float* __restrict__ x,
                                                  const float* __restrict__ mask,
                                                  const float* __restrict__ inv_delay,
                                                  const float* __restrict__ ew_w,
                                                  const float* __restrict__ ew_b,
                                                  float* __restrict__ out) {
    int blk = blockIdx.x;
    int b   = blk >> 9;                 // 512 blocks per batch
    int lane = threadIdx.x & 63;
    int wv   = threadIdx.x >> 6;
    int p = ((blk & 511) << 6) + lane;
    const float* xb = x + b * (LL * CC * PP) + p;
    int cbase = wv << 4;

    float xr[16][5];
    float s[5] = {0.f, 0.f, 0.f, 0.f, 0.f};
#pragma unroll
    for (int cc = 0; cc < 16; ++cc) {
        const float* xc = xb + (cbase + cc) * PP;
#pragma unroll
        for (int l = 0; l < LL; ++l) xr[cc][l] = xc[l * CC * PP];
        float q = xr[cc][0];
#pragma unroll
        for (int l = 0; l < LL; ++l) s[l] += q * xr[cc][l];
    }

    __shared__ float sred[4][5][64];
#pragma unroll
    for (int l = 0; l < LL; ++l) sred[wv][l][lane] = s[l];
    __syncthreads();

    // all waves redundantly finish the softmax (no second sync needed)
    float ew0 = ew_w[0], eb0 = ew_b[0];
    float m[5], t[5];
#pragma unroll
    for (int l = 0; l < LL; ++l) {
        t[l] = sred[0][l][lane] + sred[1][l][lane] + sred[2][l][lane] + sred[3][l][lane];
        float en = tanhf(inv_delay[b * LL + l] * ew0 + eb0) + 1.0f;
        m[l] = en * mask[(b * LL + l) * PP + p];
    }
    const float scale = 0.125f;               // 1/sqrt(64)
    float sc[5];
#pragma unroll
    for (int l = 0; l < LL; ++l) sc[l] = t[l] * m[0] * m[l] * scale;
    float mxv = fmaxf(fmaxf(fmaxf(sc[0], sc[1]), fmaxf(sc[2], sc[3])), sc[4]);
    float e[5], sum = 0.f;
#pragma unroll
    for (int l = 0; l < LL; ++l) { e[l] = expf(sc[l] - mxv); sum += e[l]; }
    float inv = 1.0f / sum;
    float a[5];
#pragma unroll
    for (int l = 0; l < LL; ++l) a[l] = e[l] * inv * m[l];

    float* ob = out + b * (CC * PP) + p;
#pragma unroll
    for (int cc = 0; cc < 16; ++cc) {
        float f = 0.f;
#pragma unroll
        for (int l = 0; l < LL; ++l) f += a[l] * xr[cc][l];
        ob[(cbase + cc) * PP] = f;
    }
}

// 256 blocks: block = half of one (b,c) row -> partials
__global__ void k_reduce(const float* __restrict__ xfuse,
                         float* __restrict__ avg_part,
                         float* __restrict__ mx_part) {
    int blk = blockIdx.x;               // 256
    int bc = blk >> 1;
    int half = blk & 1;
    const float4* row = (const float4*)(xfuse + bc * PP) + half * 4096;
    float s = 0.0f, m = -INFINITY;
    for (int i = threadIdx.x; i < 4096; i += 256) {
        float4 v = row[i];
        s += v.x + v.y + v.z + v.w;
        m = fmaxf(m, fmaxf(fmaxf(v.x, v.y), fmaxf(v.z, v.w)));
    }
#pragma unroll
    for (int o = 32; o > 0; o >>= 1) {
        s += __shfl_down(s, o, 64);
        m = fmaxf(m, __shfl_down(m, o, 64));
    }
    __shared__ float ss[4], sm[4];
    int lane = threadIdx.x & 63, wid = threadIdx.x >> 6;
    if (lane == 0) { ss[wid] = s; sm[wid] = m; }
    __syncthreads();
    if (threadIdx.x == 0) {
        avg_part[blk] = ss[0] + ss[1] + ss[2] + ss[3];
        mx_part[blk]  = fmaxf(fmaxf(sm[0], sm[1]), fmaxf(sm[2], sm[3]));
    }
}

__global__ void k_gate(const float* __restrict__ avg_part,
                       const float* __restrict__ mx_part,
                       const float* __restrict__ w1,   // (4,64)
                       const float* __restrict__ w2,   // (64,4)
                       float* __restrict__ gate,
                       const float* __restrict__ cnt,
                       float* __restrict__ comm_out) {
    __shared__ float hsum[BB][4];
    int t = threadIdx.x;
    if (t < BB * 4) {
        int b = t >> 2, j = t & 3;
        float ha = 0.f, hm = 0.f;
        for (int c = 0; c < CC; ++c) {
            int i = (b * CC + c) * 2;
            float av = (avg_part[i] + avg_part[i + 1]) * (1.0f / (float)PP);
            float mv = fmaxf(mx_part[i], mx_part[i + 1]);
            float wv = w1[j * CC + c];
            ha += av * wv;
            hm += mv * wv;
        }
        hsum[b][j] = fmaxf(ha, 0.0f) + fmaxf(hm, 0.0f);
    }
    __syncthreads();
    if (t < BB * CC) {
        int b = t >> 6, c = t & 63;
        float g = 0.f;
#pragma unroll
        for (int j = 0; j < 4; ++j) g += hsum[b][j] * w2[c * 4 + j];
        gate[t] = 1.0f / (1.0f + expf(-g));
    }
    if (t == 0) comm_out[0] = cnt[0] * (1.0f / (float)NP);
}

__global__ void k_scale(float* __restrict__ out, const float* __restrict__ gate) {
    int i = blockIdx.x * 256 + threadIdx.x;   // over B*C*P/4
    int bc = i >> 13;
    float g = gate[bc];
    float4* o = (float4*)out;
    float4 v = o[i];
    v.x *= g; v.y *= g; v.z *= g; v.w *= g;
    o[i] = v;
}

extern "C" void kernel_launch(void* const* d_in, const int* in_sizes, int n_in,
                              void* d_out, int out_size, void* d_ws, size_t ws_size,
                              hipStream_t stream) {
    const float* x         = (const float*)d_in[0];
    const float* psm       = (const float*)d_in[1];
    const float* inv_delay = (const float*)d_in[2];
    const float* ew_w      = (const float*)d_in[3];
    const float* ew_b      = (const float*)d_in[4];
    const float* ewc_w     = (const float*)d_in[5];
    const float* ewc_b     = (const float*)d_in[6];
    const float* w1        = (const float*)d_in[7];
    const float* w2        = (const float*)d_in[8];
    float* out = (float*)d_out;
    float* wsf = (float*)d_ws;

    float* cnt  = wsf + 32;
    float* avgp = wsf + 64;
    float* mxp  = wsf + 320;
    float* gate = wsf + 576;
    float* mask = wsf + 1024;
    float* conf = wsf + 1024 + NP;

    k_conf<<<NP / 4 / 256, 256, 0, stream>>>(psm, inv_delay, ewc_w, ewc_b, conf, cnt);
    k_mask<<<NP / 256, 256, 0, stream>>>(conf, mask, cnt);
    k_attnfuse<<<1024, 256, 0, stream>>>(x, mask, inv_delay, ew_w, ew_b, out);
    k_reduce<<<256, 256, 0, stream>>>(out, avgp, mxp);
    k_gate<<<1, 128, 0, stream>>>(avgp, mxp, w1, w2, gate, cnt, out + BB * CC * PP);
    k_scale<<<BB * CC * PP / 4 / 256, 256, 0, stream>>>(out, gate);
}